// Round 4
// baseline (200.182 us; speedup 1.0000x reference)
//
#include <hip/hip_runtime.h>
#include <hip/hip_cooperative_groups.h>
#include <math.h>

namespace cg = cooperative_groups;

#define EPS2f 0.25f
#define EPS4f 0.0625f

// ---------------------------------------------------------------------------
// Single cooperative kernel: phase 0 = table precompute (grid-wide, one wave
// per ij over blocks 0..63), grid.sync(), phase 1 = R1's main body verbatim
// (the best-measured variant: LDS broadcasts, 8-deep VMEM pipeline).
// Rationale (R0-R3 evidence): main-kernel exec is small; the window is
// fill(40us, fixed) + per-dispatch gaps (~5us each) + fixed harness cost.
// Dispatch count is the only lever the data responded to: 2 -> 1.
//
// Table layouts (unchanged):
//   AB4 (float4 view)[k2*1024 + ij] = { A(2k2), B2(2k2), A(2k2+1), B2(2k2+1) }
//        A = 1/Sigma, B2 = 2*mu_t/Sigma
//   KV4 (float4 view)[ij2*64 + k]   = { K(ij_e), Vm(ij_e), K(ij_o), Vm(ij_o) }
//   C0 [ij] = sum_k ( mu_t^2/Sigma + log(Sigma) )
// ---------------------------------------------------------------------------
__global__ __launch_bounds__(1024) void gmm_fused_kernel(
    const float* __restrict__ X,   const float* __restrict__ Mu0,
    const float* __restrict__ Mu1, const float* __restrict__ S0,
    const float* __restrict__ S1,  const float* __restrict__ Lam,
    const float* __restrict__ tptr,
    float2* __restrict__ AB2, float2* __restrict__ KV2,
    float* __restrict__ C0,
    float* __restrict__ out)
{
    __shared__ float4 Xs4[64];           // [k] = x for bb=0..3 (bcast b128)
    __shared__ float4 Wl4[1024 * 2];     // [ij][2]: slot 0 = W for bb=0..3
    __shared__ float  red[16 * 64 * 5];  // [w][k][bb], stride 5: conflict-free
    __shared__ float  XsT[4 * 64];       // [bb][k]
    __shared__ float  denpS[16 * 4];     // per-wave per-bb den partials

    const int tid  = threadIdx.x;
    const int lane = tid & 63;
    const int w    = tid >> 6;           // 0..15
    const int b0   = blockIdx.x << 2;

    // ---- X staging (input-only, no dependency on phase 0) ----
    if (tid < 256) {
        const int bb = tid >> 6, k = tid & 63;
        const float xv = X[(b0 + bb) * 64 + k];
        ((float*)&Xs4[k])[bb] = xv;
        XsT[bb * 64 + k] = xv;
    }

    // ---- Phase 0: precompute tables. gid = blk*1024+tid; one wave per ij.
    // Only blocks 0..63 participate (65536 entries / 1024 thr). ----
    if (blockIdx.x < 64) {
        const int gid = (blockIdx.x << 10) + tid;
        const int ij  = gid >> 6;            // wave-uniform (wave = 64 gids)
        const int k   = gid & 63;            // = lane
        const int i   = ij >> 5;
        const int j   = ij & 31;
        const float t   = *tptr;
        const float omt = 1.0f - t;

        const float s0 = S0[i * 64 + k];
        const float s1 = S1[j * 64 + k];
        const float m0 = Mu0[i * 64 + k];
        const float m1 = Mu1[j * 64 + k];

        const float ds  = sqrtf(4.0f * s0 * s1 + EPS4f);
        const float cs  = 0.5f * (ds - EPS2f);
        const float mt  = omt * m0 + t * m1;
        const float sig = omt * omt * s0 + t * t * s1
                        + 2.0f * t * omt * (cs + 0.5f * EPS2f);
        const float isig = 1.0f / sig;
        const float st = t * s1 - omt * s0 + (omt - t) * cs - EPS2f * t;
        const float kk = st * isig;
        const float v  = m1 - m0;

        AB2[((k >> 1) << 11) + (ij << 1) + (k & 1)] =
            make_float2(isig, 2.0f * mt * isig);
        KV2[((ij >> 1) << 7) + (k << 1) + (ij & 1)] =
            make_float2(kk, v - kk * mt);

        float c = mt * mt * isig + __logf(sig);
        #pragma unroll
        for (int off = 32; off >= 1; off >>= 1)
            c += __shfl_xor(c, off, 64);
        if (k == 0) C0[ij] = c;
    }

    __threadfence();                     // device-scope visibility of tables
    cg::this_grid().sync();              // cross-XCD barrier + fence

    const float4* __restrict__ AB4 = (const float4*)AB2;
    const float4* __restrict__ KV4 = (const float4*)KV2;

    // ---- Phase A: one ij per thread (R1 body) ----
    const int ij = tid;
    const float4* __restrict__ abp = AB4 + ij;   // stride 1024 float4 per k2
    const float c0 = C0[ij];
    const float lm = Lam[ij];

    float4 ab[8];
    #pragma unroll
    for (int g = 0; g < 8; ++g) ab[g] = abp[g << 10];

    float qa = 0.f, qb = 0.f, qc = 0.f, qd = 0.f;
    #pragma unroll
    for (int k2 = 0; k2 < 32; ++k2) {
        const float4 a = ab[k2 & 7];
        if (k2 + 8 < 32) ab[k2 & 7] = abp[(k2 + 8) << 10];
        const float4 x0 = Xs4[2 * k2];            // LDS broadcast
        const float4 x1 = Xs4[2 * k2 + 1];
        qa = fmaf(fmaf(a.x, x0.x, -a.y), x0.x, qa);
        qb = fmaf(fmaf(a.x, x0.y, -a.y), x0.y, qb);
        qc = fmaf(fmaf(a.x, x0.z, -a.y), x0.z, qc);
        qd = fmaf(fmaf(a.x, x0.w, -a.y), x0.w, qd);
        qa = fmaf(fmaf(a.z, x1.x, -a.w), x1.x, qa);
        qb = fmaf(fmaf(a.z, x1.y, -a.w), x1.y, qb);
        qc = fmaf(fmaf(a.z, x1.z, -a.w), x1.z, qc);
        qd = fmaf(fmaf(a.z, x1.w, -a.w), x1.w, qd);
    }

    #define WCALC(q) (__expf(fminf(fmaxf(-0.5f * ((q) + c0), -50.f), 50.f)) * lm)
    float4 wv4;
    wv4.x = WCALC(qa); wv4.y = WCALC(qb); wv4.z = WCALC(qc); wv4.w = WCALC(qd);
    #undef WCALC
    Wl4[ij * 2] = wv4;                   // aligned 16B row -> ds_read_b128

    // ---- Phase B prologue: first 8 KV loads fly under the den reduction ----
    const int p0 = w << 5;               // first pair index of this wave
    float4 kvb[8];
    #pragma unroll
    for (int q = 0; q < 8; ++q) kvb[q] = KV4[((p0 + q) << 6) + lane];
    const float xk0 = XsT[0 * 64 + lane], xk1 = XsT[1 * 64 + lane];
    const float xk2 = XsT[2 * 64 + lane], xk3 = XsT[3 * 64 + lane];

    float d0 = wv4.x, d1 = wv4.y, d2 = wv4.z, d3 = wv4.w;
    #pragma unroll
    for (int off = 32; off >= 1; off >>= 1) {
        d0 += __shfl_xor(d0, off, 64);
        d1 += __shfl_xor(d1, off, 64);
        d2 += __shfl_xor(d2, off, 64);
        d3 += __shfl_xor(d3, off, 64);
    }
    if (lane == 0) {
        denpS[w * 4 + 0] = d0; denpS[w * 4 + 1] = d1;
        denpS[w * 4 + 2] = d2; denpS[w * 4 + 3] = d3;
    }

    // ---- Phase B: wave w, 32 ij-pairs, lane = k ----
    // (Wl rows [64w, 64w+64) written by this same wave: no barrier needed.)
    float n0 = 0.f, n1 = 0.f, n2 = 0.f, n3 = 0.f;
    #pragma unroll
    for (int p = 0; p < 32; ++p) {
        const float4 kv = kvb[p & 7];
        if (p + 8 < 32) kvb[p & 7] = KV4[((p0 + p + 8) << 6) + lane];
        const float4 we = Wl4[(p0 + p) * 4];           // ij_e = 2*(p0+p)
        const float4 wo = Wl4[(p0 + p) * 4 + 2];       // ij_o
        float u;
        u = fmaf(kv.x, xk0, kv.y); n0 = fmaf(we.x, u, n0);
        u = fmaf(kv.x, xk1, kv.y); n1 = fmaf(we.y, u, n1);
        u = fmaf(kv.x, xk2, kv.y); n2 = fmaf(we.z, u, n2);
        u = fmaf(kv.x, xk3, kv.y); n3 = fmaf(we.w, u, n3);
        u = fmaf(kv.z, xk0, kv.w); n0 = fmaf(wo.x, u, n0);
        u = fmaf(kv.z, xk1, kv.w); n1 = fmaf(wo.y, u, n1);
        u = fmaf(kv.z, xk2, kv.w); n2 = fmaf(wo.z, u, n2);
        u = fmaf(kv.z, xk3, kv.w); n3 = fmaf(wo.w, u, n3);
    }
    {
        float* r = &red[(w * 64 + lane) * 5];
        r[0] = n0; r[1] = n1; r[2] = n2; r[3] = n3;
    }
    __syncthreads();

    // ---- Epilogue ----
    if (tid < 256) {
        const int bb = tid >> 6, k = tid & 63;   // bb wave-uniform
        float s = 0.f, d = 0.f;
        #pragma unroll
        for (int ww = 0; ww < 16; ++ww) {
            s += red[(ww * 64 + k) * 5 + bb];
            d += denpS[ww * 4 + bb];
        }
        out[(b0 + bb) * 64 + k] = s / d;
    }
}

extern "C" void kernel_launch(void* const* d_in, const int* in_sizes, int n_in,
                              void* d_out, int out_size, void* d_ws, size_t ws_size,
                              hipStream_t stream) {
    const float* X   = (const float*)d_in[0];
    const float* Mu0 = (const float*)d_in[1];
    const float* Mu1 = (const float*)d_in[2];
    const float* S0  = (const float*)d_in[3];
    const float* S1  = (const float*)d_in[4];
    const float* Lam = (const float*)d_in[5];
    const float* t   = (const float*)d_in[6];
    float* out = (float*)d_out;

    char* ws = (char*)d_ws;
    float2* AB2 = (float2*)(ws);                  // 512 KiB
    float2* KV2 = (float2*)(ws + (512 << 10));    // 512 KiB
    float*  C0  = (float*)(ws + (1024 << 10));    // 4 KiB

    void* args[] = { (void*)&X, (void*)&Mu0, (void*)&Mu1, (void*)&S0,
                     (void*)&S1, (void*)&Lam, (void*)&t,
                     (void*)&AB2, (void*)&KV2, (void*)&C0, (void*)&out };
    hipLaunchCooperativeKernel((const void*)gmm_fused_kernel,
                               dim3(256), dim3(1024), args, 0, stream);
}

// Round 5
// 144.291 us; speedup vs baseline: 1.3874x; 1.3874x over previous
//
#include <hip/hip_runtime.h>
#include <math.h>

#define EPS2f 0.25f
#define EPS4f 0.0625f

// readlane with compile-time lane: wave-uniform broadcast from a register,
// result lands in an SGPR (free operand on the consuming v_fma).
__device__ __forceinline__ float rl(float v, int l) {
    return __int_as_float(__builtin_amdgcn_readlane(__float_as_int(v), l));
}

// ---------------------------------------------------------------------------
// Single main kernel (R5). Grid 512 x 256, 2 blocks/CU (LDS-limited).
// Block b: rowgroup g = b>>4 (rows 32g..32g+31), ij-chunk c = b&15
// (ij 64c..64c+63). Tables for the chunk are computed IN-BLOCK into LDS
// (4096 entries, ~0.3us, VALU-trivial per R4's 5.7% VALUBusy evidence) --
// no precomp dispatch, no global table round-trip (was 1MiB write + 256MiB
// aggregate re-read through L1/L2 in R0-R2).
// Partials (8KiB/block) go to workspace; the LAST block per rowgroup
// (atomicAdd ticket on a memset-zeroed counter + __threadfence, the G16
// device-scope pattern) sums 16 chunk-partials and writes out.
//
// LDS layouts (padded to 65 float4s/row: row stride 1040B -> bank advance 4
// per row, so the hot ds_read_b128 streams are conflict-free and the
// one-time writes are <=8-way):
//   abL[k2][ij_loc] = { A(2k2), B2(2k2), A(2k2+1), B2(2k2+1) },  A=1/Sig,
//                     B2=2*mu_t/Sig  (phase A reads [k2][lane], lane=ij)
//   kvL[p][k]       = { K(ij_e), Vm(ij_e), K(ij_o), Vm(ij_o) }, pair p
//                     (phase B reads [p][lane], lane=k)
//   c0L[ij_loc]     = sum_k ( mu_t^2/Sig + log(Sig) )
// ---------------------------------------------------------------------------
__global__ __launch_bounds__(256, 2) void gmm_chunk_kernel(
    const float* __restrict__ X,   const float* __restrict__ Mu0,
    const float* __restrict__ Mu1, const float* __restrict__ S0,
    const float* __restrict__ S1,  const float* __restrict__ Lam,
    const float* __restrict__ tptr,
    float* __restrict__ nump, float* __restrict__ denp,
    unsigned int* __restrict__ ctr, float* __restrict__ out)
{
    __shared__ float4 abL[32][65];
    __shared__ float4 kvL[32][65];
    __shared__ float  c0L[64];
    __shared__ int    lastFlag;

    const int tid  = threadIdx.x;
    const int lane = tid & 63;
    const int w    = tid >> 6;            // 0..3
    const int g    = blockIdx.x >> 4;     // rowgroup 0..31
    const int c    = blockIdx.x & 15;     // ij-chunk 0..15
    const int r0   = (g << 5) + (w << 3); // this wave's first batch row

    // ---- Table generation: thread t owns ij_locs [ijb, ijb+8) x k={2m,2m+1}
    const int m   = tid & 31;             // k2 = m
    const int ijb = (tid >> 5) << 3;      // 0,8,...,56
    const float t   = *tptr;
    const float omt = 1.0f - t;

    float Kr[8][2], Vr[8][2], cpart[8];   // static-indexed (rule #20)
    #pragma unroll
    for (int v = 0; v < 8; ++v) {
        const int ij = (c << 6) + ijb + v;
        const int i  = ij >> 5;
        const int j  = ij & 31;
        float4 abv;
        float  csum = 0.f;
        #pragma unroll
        for (int r = 0; r < 2; ++r) {
            const int k  = 2 * m + r;
            const float s0 = S0[i * 64 + k];
            const float s1 = S1[j * 64 + k];
            const float m0 = Mu0[i * 64 + k];
            const float m1 = Mu1[j * 64 + k];
            const float dsq = sqrtf(4.0f * s0 * s1 + EPS4f);
            const float cs  = 0.5f * (dsq - EPS2f);
            const float mt  = omt * m0 + t * m1;
            const float sig = omt * omt * s0 + t * t * s1
                            + 2.0f * t * omt * (cs + 0.5f * EPS2f);
            const float isig = 1.0f / sig;
            const float st  = t * s1 - omt * s0 + (omt - t) * cs - EPS2f * t;
            const float kk  = st * isig;
            const float vm  = (m1 - m0) - kk * mt;
            if (r == 0) { abv.x = isig; abv.y = 2.0f * mt * isig; }
            else        { abv.z = isig; abv.w = 2.0f * mt * isig; }
            Kr[v][r] = kk; Vr[v][r] = vm;
            csum += mt * mt * isig + __logf(sig);
        }
        abL[m][ijb + v] = abv;
        cpart[v] = csum;
    }
    #pragma unroll
    for (int qq = 0; qq < 4; ++qq) {
        kvL[(ijb >> 1) + qq][2 * m] =
            make_float4(Kr[2 * qq][0], Vr[2 * qq][0],
                        Kr[2 * qq + 1][0], Vr[2 * qq + 1][0]);
        kvL[(ijb >> 1) + qq][2 * m + 1] =
            make_float4(Kr[2 * qq][1], Vr[2 * qq][1],
                        Kr[2 * qq + 1][1], Vr[2 * qq + 1][1]);
    }
    // C0: reduce cpart over the 32 threads sharing ijb (xor<=16 keeps groups)
    #pragma unroll
    for (int v = 0; v < 8; ++v) {
        float cc = cpart[v];
        #pragma unroll
        for (int off = 16; off >= 1; off >>= 1)
            cc += __shfl_xor(cc, off, 64);
        if (m == 0) c0L[ijb + v] = cc;
    }

    // per-lane X for this wave's 8 rows (lane = k in phase B; readlane
    // provides x[2k2],x[2k2+1] in phase A)
    float xr[8];
    #pragma unroll
    for (int u = 0; u < 8; ++u) xr[u] = X[(r0 + u) * 64 + lane];

    __syncthreads();

    // ---- Phase A: lane = ij_loc; accumulate logits for 8 rows ----
    const float c0v = c0L[lane];
    const float lm  = Lam[(c << 6) + lane];
    float q[8] = {0.f, 0.f, 0.f, 0.f, 0.f, 0.f, 0.f, 0.f};
    #pragma unroll
    for (int k2 = 0; k2 < 32; ++k2) {
        const float4 a = abL[k2][lane];          // conflict-free b128
        #pragma unroll
        for (int u = 0; u < 8; ++u) {
            const float xe = rl(xr[u], 2 * k2);
            const float xo = rl(xr[u], 2 * k2 + 1);
            q[u] = fmaf(fmaf(a.x, xe, -a.y), xe, q[u]);
            q[u] = fmaf(fmaf(a.z, xo, -a.w), xo, q[u]);
        }
    }

    float wv[8];
    #pragma unroll
    for (int u = 0; u < 8; ++u)
        wv[u] = __expf(fminf(fmaxf(-0.5f * (q[u] + c0v), -50.f), 50.f)) * lm;

    // den partial: butterfly over the wave's 64 ij
    float dsum[8];
    #pragma unroll
    for (int u = 0; u < 8; ++u) dsum[u] = wv[u];
    #pragma unroll
    for (int off = 32; off >= 1; off >>= 1) {
        #pragma unroll
        for (int u = 0; u < 8; ++u) dsum[u] += __shfl_xor(dsum[u], off, 64);
    }

    // ---- Phase B: lane = k; loop the chunk's 32 ij-pairs ----
    float nacc[8] = {0.f, 0.f, 0.f, 0.f, 0.f, 0.f, 0.f, 0.f};
    #pragma unroll
    for (int p = 0; p < 32; ++p) {
        const float4 kv = kvL[p][lane];          // conflict-free b128
        #pragma unroll
        for (int u = 0; u < 8; ++u) {
            const float We = rl(wv[u], 2 * p);
            const float Wo = rl(wv[u], 2 * p + 1);
            const float ue = fmaf(kv.x, xr[u], kv.y);
            nacc[u] = fmaf(We, ue, nacc[u]);
            const float uo = fmaf(kv.z, xr[u], kv.w);
            nacc[u] = fmaf(Wo, uo, nacc[u]);
        }
    }

    // ---- Store partials: nump[b][row32][k64], denp[b][row32] ----
    const int b = blockIdx.x;
    #pragma unroll
    for (int u = 0; u < 8; ++u)
        nump[(b * 32 + (w << 3) + u) * 64 + lane] = nacc[u];   // coalesced
    float dv = dsum[0];
    #pragma unroll
    for (int u = 1; u < 8; ++u) dv = (lane == u) ? dsum[u] : dv;
    if (lane < 8) denp[b * 32 + (w << 3) + lane] = dv;

    // ---- Arrival ticket; last block of rowgroup g finalizes ----
    __threadfence();                       // release: drain + L2 writeback
    __syncthreads();
    if (tid == 0) {
        const unsigned int old = atomicAdd(&ctr[g], 1u);
        lastFlag = (old == 15u);
    }
    __syncthreads();
    if (lastFlag) {
        __threadfence();                   // acquire side
        #pragma unroll
        for (int u = 0; u < 8; ++u) {
            const int row = (w << 3) + u;
            float s = 0.f, d = 0.f;
            #pragma unroll
            for (int cc2 = 0; cc2 < 16; ++cc2) {
                s += nump[((g * 16 + cc2) * 32 + row) * 64 + lane];
                d += denp[(g * 16 + cc2) * 32 + row];
            }
            out[(g * 32 + row) * 64 + lane] = s / d;
        }
    }
}

extern "C" void kernel_launch(void* const* d_in, const int* in_sizes, int n_in,
                              void* d_out, int out_size, void* d_ws, size_t ws_size,
                              hipStream_t stream) {
    const float* X   = (const float*)d_in[0];
    const float* Mu0 = (const float*)d_in[1];
    const float* Mu1 = (const float*)d_in[2];
    const float* S0  = (const float*)d_in[3];
    const float* S1  = (const float*)d_in[4];
    const float* Lam = (const float*)d_in[5];
    const float* t   = (const float*)d_in[6];
    float* out = (float*)d_out;

    char* ws = (char*)d_ws;
    float*        nump = (float*)(ws);                         // 4 MiB
    float*        denp = (float*)(ws + (4 << 20));             // 64 KiB
    unsigned int* ctr  = (unsigned int*)(ws + (4 << 20) + (64 << 10)); // 128 B

    hipMemsetAsync(ctr, 0, 32 * sizeof(unsigned int), stream);
    gmm_chunk_kernel<<<512, 256, 0, stream>>>(X, Mu0, Mu1, S0, S1, Lam, t,
                                              nump, denp, ctr, out);
}

// Round 6
// 78.813 us; speedup vs baseline: 2.5400x; 1.8308x over previous
//
#include <hip/hip_runtime.h>
#include <math.h>

#define EPS2f 0.25f
#define EPS4f 0.0625f

// ---------------------------------------------------------------------------
// Kernel 1: precompute per-(ij,k) tables (R1 version, best measured).
//   AB4 (float4 view)[k2*1024 + ij] = { A(2k2), B2(2k2), A(2k2+1), B2(2k2+1) }
//        A = 1/Sigma, B2 = 2*mu_t/Sigma
//   KV4 (float4 view)[ij2*64 + k]   = { K(ij_e), Vm(ij_e), K(ij_o), Vm(ij_o) }
//   C0 [ij] = sum_k ( mu_t^2/Sigma + log(Sigma) )
// ---------------------------------------------------------------------------
__global__ __launch_bounds__(256) void precomp_kernel(
    const float* __restrict__ Mu0, const float* __restrict__ Mu1,
    const float* __restrict__ S0,  const float* __restrict__ S1,
    const float* __restrict__ tptr,
    float2* __restrict__ AB2, float2* __restrict__ KV2,
    float* __restrict__ C0)
{
    __shared__ float2 abS[4][67];
    __shared__ float2 kvS[4][64];

    const int tid = threadIdx.x;
    const int k   = tid & 63;
    const int ijl = tid >> 6;
    const int ij0 = blockIdx.x << 2;
    const int ij  = ij0 + ijl;
    const int i   = ij >> 5;
    const int j   = ij & 31;
    const float t   = *tptr;
    const float omt = 1.0f - t;

    const float s0 = S0[i * 64 + k];
    const float s1 = S1[j * 64 + k];
    const float m0 = Mu0[i * 64 + k];
    const float m1 = Mu1[j * 64 + k];

    const float ds  = sqrtf(4.0f * s0 * s1 + EPS4f);
    const float cs  = 0.5f * (ds - EPS2f);
    const float mt  = omt * m0 + t * m1;
    const float sig = omt * omt * s0 + t * t * s1
                    + 2.0f * t * omt * (cs + 0.5f * EPS2f);
    const float isig = 1.0f / sig;
    const float st = t * s1 - omt * s0 + (omt - t) * cs - EPS2f * t;
    const float kk = st * isig;
    const float v  = m1 - m0;

    abS[ijl][k] = make_float2(isig, 2.0f * mt * isig);
    kvS[ijl][k] = make_float2(kk, v - kk * mt);

    float c = mt * mt * isig + __logf(sig);
    #pragma unroll
    for (int off = 32; off >= 1; off >>= 1)
        c += __shfl_xor(c, off, 64);
    if (k == 0) C0[ij] = c;

    __syncthreads();

    {   // AB store: tid = k2*8 + ijl2*2 + par -> 64B-chunked, near-coalesced
        const int k2   = tid >> 3;
        const int ijl2 = (tid >> 1) & 3;
        const int par  = tid & 1;
        AB2[(k2 << 11) + ((ij0 + ijl2) << 1) + par] = abS[ijl2][2 * k2 + par];
    }
    {   // KV store: fully linear in tid (bijection with consumer layout)
        const int pr  = tid >> 7;
        const int k6  = (tid >> 1) & 63;
        const int par = tid & 1;
        KV2[(blockIdx.x << 8) + tid] = kvS[(pr << 1) + par][k6];
    }
}

// ---------------------------------------------------------------------------
// Kernel 2: main (R1 body). Single delta vs R1: the first 4 KV loads are
// issued BEFORE Phase A's loop (phase-independent addresses), so Phase B's
// stream is already ~long in flight when the den reduction ends. +16 VGPR
// peak (ab[8]=32 + kvb[4]=16 + acc/x ~ <=128 cap).
// ---------------------------------------------------------------------------
__global__ __launch_bounds__(1024) void gmm_main_kernel(
    const float* __restrict__ X,   const float* __restrict__ Lam,
    const float* __restrict__ C0,
    const float4* __restrict__ AB4, const float4* __restrict__ KV4,
    float* __restrict__ out)
{
    __shared__ float4 Xs4[64];           // [k] = x for bb=0..3 (bcast b128)
    __shared__ float4 Wl4[1024 * 2];     // [ij][2]: slot 0 = W for bb=0..3
    __shared__ float  red[16 * 64 * 5];  // [w][k][bb], stride 5: conflict-free
    __shared__ float  XsT[4 * 64];       // [bb][k]
    __shared__ float  denp[16 * 4];      // per-wave per-bb den partials

    const int tid  = threadIdx.x;
    const int lane = tid & 63;
    const int w    = tid >> 6;           // 0..15
    const int b0   = blockIdx.x << 2;

    if (tid < 256) {
        const int bb = tid >> 6, k = tid & 63;
        const float xv = X[(b0 + bb) * 64 + k];
        ((float*)&Xs4[k])[bb] = xv;
        XsT[bb * 64 + k] = xv;
    }

    // ---- Phase A: one ij per thread ----
    const int ij = tid;
    const float4* __restrict__ abp = AB4 + ij;   // stride 1024 float4 per k2
    const float c0 = C0[ij];             // hoisted: overlaps with loop
    const float lm = Lam[ij];

    float4 ab[8];
    #pragma unroll
    for (int g = 0; g < 8; ++g) ab[g] = abp[g << 10];

    // Early KV prefetch (R6 delta): first 4 of phase B's stream in flight now.
    const int p0 = w << 5;               // first pair index of this wave
    float4 kvb[8];
    #pragma unroll
    for (int q = 0; q < 4; ++q) kvb[q] = KV4[((p0 + q) << 6) + lane];

    __syncthreads();

    float qa = 0.f, qb = 0.f, qc = 0.f, qd = 0.f;
    #pragma unroll
    for (int k2 = 0; k2 < 32; ++k2) {
        const float4 a = ab[k2 & 7];
        if (k2 + 8 < 32) ab[k2 & 7] = abp[(k2 + 8) << 10];
        const float4 x0 = Xs4[2 * k2];            // LDS broadcast
        const float4 x1 = Xs4[2 * k2 + 1];
        qa = fmaf(fmaf(a.x, x0.x, -a.y), x0.x, qa);
        qb = fmaf(fmaf(a.x, x0.y, -a.y), x0.y, qb);
        qc = fmaf(fmaf(a.x, x0.z, -a.y), x0.z, qc);
        qd = fmaf(fmaf(a.x, x0.w, -a.y), x0.w, qd);
        qa = fmaf(fmaf(a.z, x1.x, -a.w), x1.x, qa);
        qb = fmaf(fmaf(a.z, x1.y, -a.w), x1.y, qb);
        qc = fmaf(fmaf(a.z, x1.z, -a.w), x1.z, qc);
        qd = fmaf(fmaf(a.z, x1.w, -a.w), x1.w, qd);
    }

    #define WCALC(q) (__expf(fminf(fmaxf(-0.5f * ((q) + c0), -50.f), 50.f)) * lm)
    float4 wv4;
    wv4.x = WCALC(qa); wv4.y = WCALC(qb); wv4.z = WCALC(qc); wv4.w = WCALC(qd);
    #undef WCALC
    Wl4[ij * 2] = wv4;                   // aligned 16B row -> ds_read_b128

    // ---- Phase B prologue: remaining 4 KV loads under the den reduction ----
    #pragma unroll
    for (int q = 4; q < 8; ++q) kvb[q] = KV4[((p0 + q) << 6) + lane];
    const float xk0 = XsT[0 * 64 + lane], xk1 = XsT[1 * 64 + lane];
    const float xk2 = XsT[2 * 64 + lane], xk3 = XsT[3 * 64 + lane];

    float d0 = wv4.x, d1 = wv4.y, d2 = wv4.z, d3 = wv4.w;
    #pragma unroll
    for (int off = 32; off >= 1; off >>= 1) {
        d0 += __shfl_xor(d0, off, 64);
        d1 += __shfl_xor(d1, off, 64);
        d2 += __shfl_xor(d2, off, 64);
        d3 += __shfl_xor(d3, off, 64);
    }
    if (lane == 0) {
        denp[w * 4 + 0] = d0; denp[w * 4 + 1] = d1;
        denp[w * 4 + 2] = d2; denp[w * 4 + 3] = d3;
    }

    // ---- Phase B: wave w, 32 ij-pairs, lane = k ----
    // (Wl rows [64w, 64w+64) written by this same wave: no barrier needed.)
    float n0 = 0.f, n1 = 0.f, n2 = 0.f, n3 = 0.f;
    #pragma unroll
    for (int p = 0; p < 32; ++p) {
        const float4 kv = kvb[p & 7];
        if (p + 8 < 32) kvb[p & 7] = KV4[((p0 + p + 8) << 6) + lane];
        const float4 we = Wl4[(p0 + p) * 4];           // ij_e = 2*(p0+p)
        const float4 wo = Wl4[(p0 + p) * 4 + 2];       // ij_o
        float u;
        u = fmaf(kv.x, xk0, kv.y); n0 = fmaf(we.x, u, n0);
        u = fmaf(kv.x, xk1, kv.y); n1 = fmaf(we.y, u, n1);
        u = fmaf(kv.x, xk2, kv.y); n2 = fmaf(we.z, u, n2);
        u = fmaf(kv.x, xk3, kv.y); n3 = fmaf(we.w, u, n3);
        u = fmaf(kv.z, xk0, kv.w); n0 = fmaf(wo.x, u, n0);
        u = fmaf(kv.z, xk1, kv.w); n1 = fmaf(wo.y, u, n1);
        u = fmaf(kv.z, xk2, kv.w); n2 = fmaf(wo.z, u, n2);
        u = fmaf(kv.z, xk3, kv.w); n3 = fmaf(wo.w, u, n3);
    }
    {
        float* r = &red[(w * 64 + lane) * 5];
        r[0] = n0; r[1] = n1; r[2] = n2; r[3] = n3;
    }
    __syncthreads();

    // ---- Epilogue ----
    if (tid < 256) {
        const int bb = tid >> 6, k = tid & 63;   // bb wave-uniform
        float s = 0.f, d = 0.f;
        #pragma unroll
        for (int ww = 0; ww < 16; ++ww) {
            s += red[(ww * 64 + k) * 5 + bb];
            d += denp[ww * 4 + bb];
        }
        out[(b0 + bb) * 64 + k] = s / d;
    }
}

extern "C" void kernel_launch(void* const* d_in, const int* in_sizes, int n_in,
                              void* d_out, int out_size, void* d_ws, size_t ws_size,
                              hipStream_t stream) {
    const float* X   = (const float*)d_in[0];
    const float* Mu0 = (const float*)d_in[1];
    const float* Mu1 = (const float*)d_in[2];
    const float* S0  = (const float*)d_in[3];
    const float* S1  = (const float*)d_in[4];
    const float* Lam = (const float*)d_in[5];
    const float* t   = (const float*)d_in[6];
    float* out = (float*)d_out;

    char* ws = (char*)d_ws;
    float2* AB2 = (float2*)(ws);                  // 512 KiB
    float2* KV2 = (float2*)(ws + (512 << 10));    // 512 KiB
    float*  C0  = (float*)(ws + (1024 << 10));    // 4 KiB

    precomp_kernel<<<256, 256, 0, stream>>>(Mu0, Mu1, S0, S1, t, AB2, KV2, C0);
    gmm_main_kernel<<<256, 1024, 0, stream>>>(X, Lam, C0,
                                              (const float4*)AB2,
                                              (const float4*)KV2, out);
}